// Round 18
// baseline (53.570 us; speedup 1.0000x reference)
//
#include <hip/hip_runtime.h>
#include <math.h>

#define NB 64
#define NN 100
#define HH 128
#define HC 16
#define NCH 8

static constexpr float EPSBN = 1e-5f;

// ============ k_pre: 64 light blocks, parallel time-MLP only -> u1, Dfull ============
__global__ __launch_bounds__(256) void k_pre(
    const float* __restrict__ timev,
    const float* __restrict__ Wt1, const float* __restrict__ bt1,
    const float* __restrict__ Wt2, const float* __restrict__ bt2,
    const float* __restrict__ Wtn, const float* __restrict__ btn,
    const float* __restrict__ g_tn, const float* __restrict__ b_tn,
    const float* __restrict__ Wg1, const float* __restrict__ We1,
    const float* __restrict__ be1, const float* __restrict__ be0,
    const float* __restrict__ g_e0, const float* __restrict__ b_e0,
    float* __restrict__ u1, float* __restrict__ Dfull) {
    __shared__ float s_temb[128], s_h1[128], s_h[128], s_tn[104], spart[256];
    const int b = blockIdx.x, t = threadIdx.x;  // XCD = b%8
    const float rinv = 1.0f / sqrtf(1.f + EPSBN);
    const float tt = timev[b];
    if (t < 128) {
        int k = t & 63;
        float f = expf((float)k * (-logf(10000.f) / 63.f));
        float a = tt * f;
        s_temb[t] = (t < 64) ? sinf(a) : cosf(a);
    }
    __syncthreads();
    const int h = t & 127, half = t >> 7;
    // A: h1 = relu(temb @ Wt1 + bt1)  (2 lanes/output x 4 accs)
    {
        const float* wp = Wt1 + (half * 64) * HH + h;
        const float* e = s_temb + half * 64;
        float a0 = 0.f, a1 = 0.f, a2 = 0.f, a3 = 0.f;
#pragma unroll 4
        for (int q = 0; q < 64; q += 4) {
            a0 = fmaf(e[q + 0], wp[(q + 0) * HH], a0);
            a1 = fmaf(e[q + 1], wp[(q + 1) * HH], a1);
            a2 = fmaf(e[q + 2], wp[(q + 2) * HH], a2);
            a3 = fmaf(e[q + 3], wp[(q + 3) * HH], a3);
        }
        spart[t] = (a0 + a1) + (a2 + a3);
    }
    __syncthreads();
    if (t < 128) s_h1[t] = fmaxf(spart[t] + spart[128 + t] + bt1[t], 0.f);
    __syncthreads();
    // B: h = h1 @ Wt2 + bt2
    {
        const float* wp = Wt2 + (half * 64) * HH + h;
        const float* e = s_h1 + half * 64;
        float a0 = 0.f, a1 = 0.f, a2 = 0.f, a3 = 0.f;
#pragma unroll 4
        for (int q = 0; q < 64; q += 4) {
            a0 = fmaf(e[q + 0], wp[(q + 0) * HH], a0);
            a1 = fmaf(e[q + 1], wp[(q + 1) * HH], a1);
            a2 = fmaf(e[q + 2], wp[(q + 2) * HH], a2);
            a3 = fmaf(e[q + 3], wp[(q + 3) * HH], a3);
        }
        spart[t] = (a0 + a1) + (a2 + a3);
    }
    __syncthreads();
    if (t < 128) s_h[t] = spart[t] + spart[128 + t] + bt2[t];
    __syncthreads();
    // C: t_node = relu(bn(h @ Wtn + btn))
    if (h < NN) {
        const float* wp = Wtn + (half * 64) * NN + h;
        const float* e = s_h + half * 64;
        float a0 = 0.f, a1 = 0.f, a2 = 0.f, a3 = 0.f;
#pragma unroll 4
        for (int q = 0; q < 64; q += 4) {
            a0 = fmaf(e[q + 0], wp[(q + 0) * NN], a0);
            a1 = fmaf(e[q + 1], wp[(q + 1) * NN], a1);
            a2 = fmaf(e[q + 2], wp[(q + 2) * NN], a2);
            a3 = fmaf(e[q + 3], wp[(q + 3) * NN], a3);
        }
        spart[t] = (a0 + a1) + (a2 + a3);
    }
    __syncthreads();
    if (t < NN)
        s_tn[t] = fmaxf(fmaf(g_tn[t] * rinv, spart[t] + spart[128 + t] + btn[t],
                             b_tn[t]), 0.f);
    __syncthreads();
    // D: u1 = t_node @ Wg1[N:, :]
    {
        const float* wp = Wg1 + (NN + half * 50) * HH + h;
        const float* e = s_tn + half * 50;
        float a0 = 0.f, a1 = 0.f;
#pragma unroll 5
        for (int q = 0; q < 50; q += 2) {
            a0 = fmaf(e[q + 0], wp[(q + 0) * HH], a0);
            a1 = fmaf(e[q + 1], wp[(q + 1) * HH], a1);
        }
        spart[t] = a0 + a1;
    }
    __syncthreads();
    if (t < 128) u1[b * HH + t] = spart[t] + spart[128 + t];
    // Dfull: parallel product + tree reduce
    __syncthreads();
    if (t < 128)
        spart[t] = s_h[t] * We1[HH + t] +
                   (be0[t] * g_e0[t] * rinv + b_e0[t]) * We1[t];
    __syncthreads();
    if (t < 64) {
        float v = spart[t] + spart[t + 64];
        v += __shfl_xor(v, 1);  v += __shfl_xor(v, 2);
        v += __shfl_xor(v, 4);  v += __shfl_xor(v, 8);
        v += __shfl_xor(v, 16); v += __shfl_xor(v, 32);
        if (t == 0) Dfull[b] = v + be1[0];
    }
}

// ====== layer 1 + in-block adjacency: degrees/rs via jp-shfl row sums over X ======
// grid (NB, 8); block 256 = (jp=t&3, ig=t>>2). hcb==0 exports dinv.
__global__ __launch_bounds__(256, 2) void k_l1(
    const float* __restrict__ X, const float* __restrict__ Wg1,
    const float* __restrict__ u1, const float* __restrict__ bg1,
    const float* __restrict__ g1, const float* __restrict__ bb1,
    float* __restrict__ dinv, float* __restrict__ out) {
    __shared__ float sZ[NN * 20];
    __shared__ float sdv[NN];
    const int b = blockIdx.x, hcb = blockIdx.y, hc = hcb * HC;
    const int t = threadIdx.x, jp = t & 3, ig = t >> 2;
    const int r0 = ig, r1 = (ig < 36) ? 64 + ig : ig;
    const float* __restrict__ Xb = X + b * NN * NN;
    const int j0 = jp * 28;
    // ---- pass A: degrees (X is 0/1; row-sum + optional self-loop) ----
    float d0 = 0.f, d1 = 0.f;
#pragma unroll
    for (int s = 0; s < 7; ++s) {
        const int j = j0 + s * 4;
        if (j < NN) {
            float4 v0 = *(const float4*)&Xb[r0 * NN + j];
            float4 v1 = *(const float4*)&Xb[r1 * NN + j];
            d0 += (v0.x + v0.y) + (v0.z + v0.w);
            d1 += (v1.x + v1.y) + (v1.z + v1.w);
        }
    }
    d0 += __shfl_xor(d0, 1); d0 += __shfl_xor(d0, 2);
    d1 += __shfl_xor(d1, 1); d1 += __shfl_xor(d1, 2);
    if (jp == 0) {
        if (Xb[r0 * NN + r0] == 0.f) d0 += 1.f;
        sdv[r0] = 1.0f / sqrtf(d0);
        if (ig < 36) {
            if (Xb[r1 * NN + r1] == 0.f) d1 += 1.f;
            sdv[r1] = 1.0f / sqrtf(d1);
        }
    }
    __syncthreads();
    // ---- pass B: rs (registers; consumed by the same jp==0 thread) ----
    float rsum0 = 0.f, rsum1 = 0.f;
#pragma unroll
    for (int s = 0; s < 7; ++s) {
        const int j = j0 + s * 4;
        if (j < NN) {
            float4 v0 = *(const float4*)&Xb[r0 * NN + j];
            float4 v1 = *(const float4*)&Xb[r1 * NN + j];
#pragma unroll
            for (int jj = 0; jj < 4; ++jj) {
                const float dj = sdv[j + jj];
                float at0 = (r0 == j + jj) ? 1.f : (&v0.x)[jj];
                float at1 = (r1 == j + jj) ? 1.f : (&v1.x)[jj];
                rsum0 = fmaf(at0, dj, rsum0);
                rsum1 = fmaf(at1, dj, rsum1);
            }
        }
    }
    rsum0 += __shfl_xor(rsum0, 1); rsum0 += __shfl_xor(rsum0, 2);
    rsum1 += __shfl_xor(rsum1, 1); rsum1 += __shfl_xor(rsum1, 2);
    const float rs0 = sdv[r0] * rsum0, rs1 = sdv[r1] * rsum1;
    if (hcb == 0 && jp == 0) {
        dinv[b * NN + r0] = sdv[r0];
        if (ig < 36) dinv[b * NN + r1] = sdv[r1];
    }
    // ---- stage sZ = dinv_j * Wg1[j, hc:hc+16] ----
    for (int idx = t; idx < 400; idx += 256) {
        int j = idx >> 2, c4 = idx & 3;
        float4 w = *(const float4*)&Wg1[j * HH + hc + c4 * 4];
        float dj = sdv[j];
        *(float4*)&sZ[j * 20 + c4 * 4] = make_float4(dj * w.x, dj * w.y, dj * w.z, dj * w.w);
    }
    __syncthreads();
    // ---- layer-1 GEMM body (r12-verified) ----
    float a0[16], a1[16];
#pragma unroll
    for (int c = 0; c < 16; ++c) { a0[c] = 0.f; a1[c] = 0.f; }
#pragma unroll
    for (int s = 0; s < 7; ++s) {
        const int j = j0 + s * 4;
        if (j < NN) {
            float4 v0 = *(const float4*)&Xb[r0 * NN + j];
            float4 v1 = *(const float4*)&Xb[r1 * NN + j];
#pragma unroll
            for (int jj = 0; jj < 4; ++jj) {
                const float e0 = (&v0.x)[jj], e1 = (&v1.x)[jj];
                const int zr = (j + jj) * 20;
#pragma unroll
                for (int c4 = 0; c4 < 4; ++c4) {
                    float4 z = *(const float4*)&sZ[zr + c4 * 4];
                    a0[c4 * 4 + 0] = fmaf(e0, z.x, a0[c4 * 4 + 0]);
                    a0[c4 * 4 + 1] = fmaf(e0, z.y, a0[c4 * 4 + 1]);
                    a0[c4 * 4 + 2] = fmaf(e0, z.z, a0[c4 * 4 + 2]);
                    a0[c4 * 4 + 3] = fmaf(e0, z.w, a0[c4 * 4 + 3]);
                    a1[c4 * 4 + 0] = fmaf(e1, z.x, a1[c4 * 4 + 0]);
                    a1[c4 * 4 + 1] = fmaf(e1, z.y, a1[c4 * 4 + 1]);
                    a1[c4 * 4 + 2] = fmaf(e1, z.z, a1[c4 * 4 + 2]);
                    a1[c4 * 4 + 3] = fmaf(e1, z.w, a1[c4 * 4 + 3]);
                }
            }
        }
    }
#pragma unroll
    for (int c = 0; c < 16; ++c) {
        a0[c] += __shfl_xor(a0[c], 1); a0[c] += __shfl_xor(a0[c], 2);
        a1[c] += __shfl_xor(a1[c], 1); a1[c] += __shfl_xor(a1[c], 2);
    }
    if (jp == 0) {
        const float rinv = 1.0f / sqrtf(1.f + EPSBN);
        const float di0 = sdv[r0], di1 = sdv[r1];
        const float cr0 = 1.f - Xb[r0 * NN + r0];
        const float cr1 = 1.f - Xb[r1 * NN + r1];
        float* ob = out + b * NN * HH;
#pragma unroll
        for (int c4 = 0; c4 < 4; ++c4) {
            float4 gv = *(const float4*)&g1[hc + c4 * 4];
            float4 bbv = *(const float4*)&bb1[hc + c4 * 4];
            float4 bgv = *(const float4*)&bg1[hc + c4 * 4];
            float4 uv = *(const float4*)&u1[b * HH + hc + c4 * 4];
            float4 y0, y1;
#pragma unroll
            for (int cc = 0; cc < 4; ++cc) {
                const int c = c4 * 4 + cc;
                float s0 = di0 * fmaf(cr0, sZ[r0 * 20 + c], a0[c]);
                float s1 = di1 * fmaf(cr1, sZ[r1 * 20 + c], a1[c]);
                (&y0.x)[cc] = fmaxf(fmaf((&gv.x)[cc] * rinv,
                                         s0 + rs0 * (&uv.x)[cc] + (&bgv.x)[cc],
                                         (&bbv.x)[cc]), 0.f);
                (&y1.x)[cc] = fmaxf(fmaf((&gv.x)[cc] * rinv,
                                         s1 + rs1 * (&uv.x)[cc] + (&bgv.x)[cc],
                                         (&bbv.x)[cc]), 0.f);
            }
            *(float4*)&ob[r0 * HH + hc + c4 * 4] = y0;
            if (ig < 36) *(float4*)&ob[r1 * HH + hc + c4 * 4] = y1;
        }
    }
}

// ====== fused layer (r12/r14-verified). LAST: in-block vi/vj + psi/psj ======
template <bool LAST>
__global__ __launch_bounds__(256, 2) void k_layer(
    const float* __restrict__ X, const float* __restrict__ dinv,
    const float* __restrict__ xin, const float* __restrict__ W,
    const float* __restrict__ bg, const float* __restrict__ g,
    const float* __restrict__ bb,
    const float* __restrict__ We0, const float* __restrict__ We1,
    const float* __restrict__ g_e0,
    float* __restrict__ out, float* __restrict__ psi, float* __restrict__ psj) {
    __shared__ float sW[128 * 16];  // [k'][16], k' = (k&31)*4 + (k>>5)
    __shared__ float sZ[NN * 20];
    __shared__ float sdv[NN];
    __shared__ float sc[128], sVi[16], sVj[16];
    const int b = blockIdx.x, hcb = blockIdx.y, hc = hcb * HC;
    const int t = threadIdx.x, jp = t & 3, ig = t >> 2;
    const float rinv = 1.0f / sqrtf(1.f + EPSBN);
    if (t < NN) sdv[t] = dinv[b * NN + t];
    if (LAST && t >= 112 && t < 240) sc[t - 112] = g_e0[t - 112] * We1[t - 112] * rinv;
    for (int idx = t; idx < 512; idx += 256) {
        int k = idx >> 2, c4 = idx & 3;
        int kp = ((k & 31) << 2) | (k >> 5);
        *(float4*)&sW[kp * 16 + c4 * 4] = *(const float4*)&W[k * HH + hc + c4 * 4];
    }
    __syncthreads();
    if (LAST && t < 32) {
        const int h = hc + (t & 15);
        const float* row = We0 + ((t < 16) ? h : (HH + h)) * HH;
        float a = 0.f;
        for (int hh = 0; hh < HH; ++hh) a = fmaf(row[hh], sc[hh], a);
        if (t < 16) sVi[t] = a; else sVj[t - 16] = a;
    }
    const int r0 = ig, r1 = (ig < 36) ? 64 + ig : ig;
    const float* __restrict__ xb = xin + b * NN * HH;
    float a0[16], a1[16];
#pragma unroll
    for (int c = 0; c < 16; ++c) { a0[c] = 0.f; a1[c] = 0.f; }
    const int wb = jp << 4;
#pragma unroll
    for (int s = 0; s < 8; ++s) {
        const int k = (jp << 5) + s * 4;
        float4 x0 = *(const float4*)&xb[r0 * HH + k];
        float4 x1 = *(const float4*)&xb[r1 * HH + k];
#pragma unroll
        for (int kk = 0; kk < 4; ++kk) {
            const float e0 = (&x0.x)[kk], e1 = (&x1.x)[kk];
            const int wr = ((s * 4 + kk) << 6) + wb;
#pragma unroll
            for (int c4 = 0; c4 < 4; ++c4) {
                float4 w = *(const float4*)&sW[wr + c4 * 4];
                a0[c4 * 4 + 0] = fmaf(e0, w.x, a0[c4 * 4 + 0]);
                a0[c4 * 4 + 1] = fmaf(e0, w.y, a0[c4 * 4 + 1]);
                a0[c4 * 4 + 2] = fmaf(e0, w.z, a0[c4 * 4 + 2]);
                a0[c4 * 4 + 3] = fmaf(e0, w.w, a0[c4 * 4 + 3]);
                a1[c4 * 4 + 0] = fmaf(e1, w.x, a1[c4 * 4 + 0]);
                a1[c4 * 4 + 1] = fmaf(e1, w.y, a1[c4 * 4 + 1]);
                a1[c4 * 4 + 2] = fmaf(e1, w.z, a1[c4 * 4 + 2]);
                a1[c4 * 4 + 3] = fmaf(e1, w.w, a1[c4 * 4 + 3]);
            }
        }
    }
#pragma unroll
    for (int c = 0; c < 16; ++c) {
        a0[c] += __shfl_xor(a0[c], 1); a0[c] += __shfl_xor(a0[c], 2);
        a1[c] += __shfl_xor(a1[c], 1); a1[c] += __shfl_xor(a1[c], 2);
    }
    if (jp == 0) {
        const float di0 = sdv[r0], di1 = sdv[r1];
#pragma unroll
        for (int c4 = 0; c4 < 4; ++c4) {
            *(float4*)&sZ[r0 * 20 + c4 * 4] =
                make_float4(di0 * a0[c4 * 4 + 0], di0 * a0[c4 * 4 + 1],
                            di0 * a0[c4 * 4 + 2], di0 * a0[c4 * 4 + 3]);
            if (ig < 36)
                *(float4*)&sZ[r1 * 20 + c4 * 4] =
                    make_float4(di1 * a1[c4 * 4 + 0], di1 * a1[c4 * 4 + 1],
                                di1 * a1[c4 * 4 + 2], di1 * a1[c4 * 4 + 3]);
        }
    }
    __syncthreads();
#pragma unroll
    for (int c = 0; c < 16; ++c) { a0[c] = 0.f; a1[c] = 0.f; }
    const float* __restrict__ Xb = X + b * NN * NN;
    const int j0 = jp * 28;
#pragma unroll
    for (int s = 0; s < 7; ++s) {
        const int j = j0 + s * 4;
        if (j < NN) {
            float4 v0 = *(const float4*)&Xb[r0 * NN + j];
            float4 v1 = *(const float4*)&Xb[r1 * NN + j];
#pragma unroll
            for (int jj = 0; jj < 4; ++jj) {
                const float e0 = (&v0.x)[jj], e1 = (&v1.x)[jj];
                const int zr = (j + jj) * 20;
#pragma unroll
                for (int c4 = 0; c4 < 4; ++c4) {
                    float4 z = *(const float4*)&sZ[zr + c4 * 4];
                    a0[c4 * 4 + 0] = fmaf(e0, z.x, a0[c4 * 4 + 0]);
                    a0[c4 * 4 + 1] = fmaf(e0, z.y, a0[c4 * 4 + 1]);
                    a0[c4 * 4 + 2] = fmaf(e0, z.z, a0[c4 * 4 + 2]);
                    a0[c4 * 4 + 3] = fmaf(e0, z.w, a0[c4 * 4 + 3]);
                    a1[c4 * 4 + 0] = fmaf(e1, z.x, a1[c4 * 4 + 0]);
                    a1[c4 * 4 + 1] = fmaf(e1, z.y, a1[c4 * 4 + 1]);
                    a1[c4 * 4 + 2] = fmaf(e1, z.z, a1[c4 * 4 + 2]);
                    a1[c4 * 4 + 3] = fmaf(e1, z.w, a1[c4 * 4 + 3]);
                }
            }
        }
    }
#pragma unroll
    for (int c = 0; c < 16; ++c) {
        a0[c] += __shfl_xor(a0[c], 1); a0[c] += __shfl_xor(a0[c], 2);
        a1[c] += __shfl_xor(a1[c], 1); a1[c] += __shfl_xor(a1[c], 2);
    }
    if (jp == 0) {
        const float di0 = sdv[r0], di1 = sdv[r1];
        const float cr0 = 1.f - Xb[r0 * NN + r0];
        const float cr1 = 1.f - Xb[r1 * NN + r1];
        float y0[16], y1[16];
#pragma unroll
        for (int c4 = 0; c4 < 4; ++c4) {
            float4 gv = *(const float4*)&g[hc + c4 * 4];
            float4 bbv = *(const float4*)&bb[hc + c4 * 4];
            float4 bgv = *(const float4*)&bg[hc + c4 * 4];
#pragma unroll
            for (int cc = 0; cc < 4; ++cc) {
                const int c = c4 * 4 + cc;
                float s0 = di0 * fmaf(cr0, sZ[r0 * 20 + c], a0[c]);
                float s1 = di1 * fmaf(cr1, sZ[r1 * 20 + c], a1[c]);
                y0[c] = fmaxf(fmaf((&gv.x)[cc] * rinv, s0 + (&bgv.x)[cc], (&bbv.x)[cc]), 0.f);
                y1[c] = fmaxf(fmaf((&gv.x)[cc] * rinv, s1 + (&bgv.x)[cc], (&bbv.x)[cc]), 0.f);
            }
        }
        if (LAST) {
            float pi0 = 0.f, pj0 = 0.f, pi1 = 0.f, pj1 = 0.f;
#pragma unroll
            for (int c = 0; c < 16; ++c) {
                pi0 = fmaf(y0[c], sVi[c], pi0); pj0 = fmaf(y0[c], sVj[c], pj0);
                pi1 = fmaf(y1[c], sVi[c], pi1); pj1 = fmaf(y1[c], sVj[c], pj1);
            }
            psi[(b * NN + r0) * NCH + hcb] = pi0;
            psj[(b * NN + r0) * NCH + hcb] = pj0;
            if (ig < 36) {
                psi[(b * NN + r1) * NCH + hcb] = pi1;
                psj[(b * NN + r1) * NCH + hcb] = pj1;
            }
        } else {
            float* ob = out + b * NN * HH;
#pragma unroll
            for (int c4 = 0; c4 < 4; ++c4) {
                *(float4*)&ob[r0 * HH + hc + c4 * 4] =
                    make_float4(y0[c4 * 4 + 0], y0[c4 * 4 + 1], y0[c4 * 4 + 2], y0[c4 * 4 + 3]);
                if (ig < 36)
                    *(float4*)&ob[r1 * HH + hc + c4 * 4] =
                        make_float4(y1[c4 * 4 + 0], y1[c4 * 4 + 1], y1[c4 * 4 + 2], y1[c4 * 4 + 3]);
            }
        }
    }
}

// ============ out[b,i,j] = (i!=j) * bn(si+sj+D) (r12-verified) ============
__global__ __launch_bounds__(256) void k_out(
    const float* __restrict__ psi, const float* __restrict__ psj,
    const float* __restrict__ Dfull, const float* __restrict__ g_e1,
    const float* __restrict__ b_e1, float* __restrict__ outp) {
    __shared__ float ssi[25], ssj[NN];
    const int b = blockIdx.x, i0 = blockIdx.y * 25;
    const int t = threadIdx.x;
    if (t < NN) {
        float s = 0.f;
        const float4* p = (const float4*)(psj + (b * NN + t) * NCH);
#pragma unroll
        for (int q = 0; q < NCH / 4; ++q) {
            float4 v = p[q];
            s += v.x + v.y + v.z + v.w;
        }
        ssj[t] = s;
    }
    if (t >= 128 && t < 128 + 25) {
        int i = t - 128;
        float s = 0.f;
        const float4* p = (const float4*)(psi + (b * NN + i0 + i) * NCH);
#pragma unroll
        for (int q = 0; q < NCH / 4; ++q) {
            float4 v = p[q];
            s += v.x + v.y + v.z + v.w;
        }
        ssi[i] = s;
    }
    __syncthreads();
    const float rinv = 1.0f / sqrtf(1.f + EPSBN);
    const float D = Dfull[b], ge = g_e1[0] * rinv, be = b_e1[0];
    float* ob = outp + b * NN * NN + i0 * NN;
    for (int e = t; e < 25 * NN; e += 256) {
        int ii = e / NN, j = e - ii * NN;
        float v = fmaf(ge, ssi[ii] + ssj[j] + D, be);
        ob[e] = (i0 + ii == j) ? 0.f : v;
    }
}

extern "C" void kernel_launch(void* const* d_in, const int* in_sizes, int n_in,
                              void* d_out, int out_size, void* d_ws, size_t ws_size,
                              hipStream_t stream) {
    const float* X    = (const float*)d_in[0];
    const float* timev= (const float*)d_in[1];
    const float* Wt1  = (const float*)d_in[2];
    const float* bt1  = (const float*)d_in[3];
    const float* Wt2  = (const float*)d_in[4];
    const float* bt2  = (const float*)d_in[5];
    const float* Wtn  = (const float*)d_in[6];
    const float* btn  = (const float*)d_in[7];
    const float* g_tn = (const float*)d_in[8];
    const float* b_tn = (const float*)d_in[9];
    const float* Wg1  = (const float*)d_in[10];
    const float* bg1  = (const float*)d_in[11];
    const float* g1   = (const float*)d_in[12];
    const float* bb1  = (const float*)d_in[13];
    const float* Wg2  = (const float*)d_in[14];
    const float* bg2  = (const float*)d_in[15];
    const float* g2   = (const float*)d_in[16];
    const float* bb2  = (const float*)d_in[17];
    const float* Wg3  = (const float*)d_in[18];
    const float* bg3  = (const float*)d_in[19];
    const float* g3   = (const float*)d_in[20];
    const float* bb3  = (const float*)d_in[21];
    const float* We0  = (const float*)d_in[22];
    const float* be0  = (const float*)d_in[23];
    const float* g_e0 = (const float*)d_in[24];
    const float* b_e0 = (const float*)d_in[25];
    const float* We1  = (const float*)d_in[26];
    const float* be1  = (const float*)d_in[27];
    const float* g_e1 = (const float*)d_in[28];
    const float* b_e1 = (const float*)d_in[29];

    float* ws = (float*)d_ws;
    float* dinv  = ws;            // 6400
    float* u1    = dinv + 6400;   // 8192
    float* Dfull = u1 + 8192;     // 64
    float* x1    = Dfull + 64;    // 819200 (dead after layer2 -> psi/psj alias)
    float* x2    = x1 + 819200;   // 819200
    float* psi   = x1;            // 51200
    float* psj   = x1 + 51200;    // 51200

    k_pre<<<dim3(NB), dim3(256), 0, stream>>>(
        timev, Wt1, bt1, Wt2, bt2, Wtn, btn, g_tn, b_tn, Wg1, We1, be1,
        be0, g_e0, b_e0, u1, Dfull);

    k_l1<<<dim3(NB, NCH), dim3(256), 0, stream>>>(X, Wg1, u1, bg1, g1, bb1, dinv, x1);
    k_layer<false><<<dim3(NB, NCH), dim3(256), 0, stream>>>(
        X, dinv, x1, Wg2, bg2, g2, bb2,
        nullptr, nullptr, nullptr, x2, nullptr, nullptr);
    k_layer<true><<<dim3(NB, NCH), dim3(256), 0, stream>>>(
        X, dinv, x2, Wg3, bg3, g3, bb3,
        We0, We1, g_e0, nullptr, psi, psj);

    k_out<<<dim3(NB, 4), dim3(256), 0, stream>>>(psi, psj, Dfull, g_e1, b_e1,
                                                 (float*)d_out);
}

// Round 19
// 48.458 us; speedup vs baseline: 1.1055x; 1.1055x over previous
//
#include <hip/hip_runtime.h>
#include <math.h>

#define NB 64
#define NN 100
#define HH 128
#define HC 16
#define NCH 8

static constexpr float EPSBN = 1e-5f;

// ============ k_pre: adjacency (0-63), PARALLEL time MLP (64-127), vij (128) ============
__global__ __launch_bounds__(256) void k_pre(
    const float* __restrict__ X, const float* __restrict__ timev,
    const float* __restrict__ Wt1, const float* __restrict__ bt1,
    const float* __restrict__ Wt2, const float* __restrict__ bt2,
    const float* __restrict__ Wtn, const float* __restrict__ btn,
    const float* __restrict__ g_tn, const float* __restrict__ b_tn,
    const float* __restrict__ Wg1, const float* __restrict__ We0,
    const float* __restrict__ We1, const float* __restrict__ be1,
    const float* __restrict__ be0, const float* __restrict__ g_e0,
    const float* __restrict__ b_e0,
    float* __restrict__ dinv, float* __restrict__ rs,
    float* __restrict__ u1, float* __restrict__ Dfull,
    float* __restrict__ vi, float* __restrict__ vj) {
    __shared__ float sX[NN * NN];
    __shared__ float sdinv[104];
    const int bx = blockIdx.x, t = threadIdx.x;
    const float rinv = 1.0f / sqrtf(1.f + EPSBN);

    if (bx < NB) {
        // ---- adjacency stats for batch b = bx (XCD b%8) ----
        const int b = bx;
        float4* s4 = (float4*)sX;
        const float4* X4 = (const float4*)(X + b * NN * NN);
        for (int idx = t; idx < NN * NN / 4; idx += 256) s4[idx] = X4[idx];
        __syncthreads();
        if (t < 200) {
            const int row = t >> 1, h = t & 1;
            const float4* r4 = (const float4*)(sX + row * NN);
            float d = 0.f;
            const int qs = h ? 13 : 0, qe = h ? 25 : 13;
            for (int q = qs; q < qe; ++q) {
                float4 v = r4[q];
                d += v.x + v.y + v.z + v.w;  // X is 0/1
            }
            d += __shfl_xor(d, 1);
            if (h == 0) {
                if (sX[row * NN + row] == 0.f) d += 1.f;
                sdinv[row] = 1.0f / sqrtf(d);
            }
        }
        __syncthreads();
        if (t < 200) {
            const int row = t >> 1, h = t & 1;
            float ssum = 0.f;
            for (int j = h; j < NN; j += 2) {
                float x = sX[row * NN + j];
                float at = (row == j) ? 1.f : x;
                ssum += at * sdinv[j];
            }
            ssum += __shfl_xor(ssum, 1);
            if (h == 0) {
                rs[b * NN + row] = sdinv[row] * ssum;
                dinv[b * NN + row] = sdinv[row];
            }
        }
        return;
    }
    if (bx < 2 * NB) {
        // ---- parallel time MLP for b = bx-64 ((64+b)%8 == b%8) ----
        const int b = bx - NB;
        float* s_temb = sX;          // 128
        float* s_h1 = sX + 128;      // 128
        float* s_h = sX + 256;       // 128
        float* s_tn = sX + 384;      // 104
        float* spart = sX + 512;     // 256
        const float tt = timev[b];
        if (t < 128) {
            int k = t & 63;
            float f = expf((float)k * (-logf(10000.f) / 63.f));
            float a = tt * f;
            s_temb[t] = (t < 64) ? sinf(a) : cosf(a);
        }
        __syncthreads();
        const int h = t & 127, half = t >> 7;
        // A: h1 = relu(temb @ Wt1 + bt1)  (2 lanes/output x 4 accs)
        {
            const float* wp = Wt1 + (half * 64) * HH + h;
            const float* e = s_temb + half * 64;
            float a0 = 0.f, a1 = 0.f, a2 = 0.f, a3 = 0.f;
#pragma unroll 4
            for (int q = 0; q < 64; q += 4) {
                a0 = fmaf(e[q + 0], wp[(q + 0) * HH], a0);
                a1 = fmaf(e[q + 1], wp[(q + 1) * HH], a1);
                a2 = fmaf(e[q + 2], wp[(q + 2) * HH], a2);
                a3 = fmaf(e[q + 3], wp[(q + 3) * HH], a3);
            }
            spart[t] = (a0 + a1) + (a2 + a3);
        }
        __syncthreads();
        if (t < 128) s_h1[t] = fmaxf(spart[t] + spart[128 + t] + bt1[t], 0.f);
        __syncthreads();
        // B: h = h1 @ Wt2 + bt2
        {
            const float* wp = Wt2 + (half * 64) * HH + h;
            const float* e = s_h1 + half * 64;
            float a0 = 0.f, a1 = 0.f, a2 = 0.f, a3 = 0.f;
#pragma unroll 4
            for (int q = 0; q < 64; q += 4) {
                a0 = fmaf(e[q + 0], wp[(q + 0) * HH], a0);
                a1 = fmaf(e[q + 1], wp[(q + 1) * HH], a1);
                a2 = fmaf(e[q + 2], wp[(q + 2) * HH], a2);
                a3 = fmaf(e[q + 3], wp[(q + 3) * HH], a3);
            }
            spart[t] = (a0 + a1) + (a2 + a3);
        }
        __syncthreads();
        if (t < 128) s_h[t] = spart[t] + spart[128 + t] + bt2[t];
        __syncthreads();
        // C: t_node = relu(bn(h @ Wtn + btn))
        if (h < NN) {
            const float* wp = Wtn + (half * 64) * NN + h;
            const float* e = s_h + half * 64;
            float a0 = 0.f, a1 = 0.f, a2 = 0.f, a3 = 0.f;
#pragma unroll 4
            for (int q = 0; q < 64; q += 4) {
                a0 = fmaf(e[q + 0], wp[(q + 0) * NN], a0);
                a1 = fmaf(e[q + 1], wp[(q + 1) * NN], a1);
                a2 = fmaf(e[q + 2], wp[(q + 2) * NN], a2);
                a3 = fmaf(e[q + 3], wp[(q + 3) * NN], a3);
            }
            spart[t] = (a0 + a1) + (a2 + a3);
        }
        __syncthreads();
        if (t < NN)
            s_tn[t] = fmaxf(fmaf(g_tn[t] * rinv, spart[t] + spart[128 + t] + btn[t],
                                 b_tn[t]), 0.f);
        __syncthreads();
        // D: u1 = t_node @ Wg1[N:, :]
        {
            const float* wp = Wg1 + (NN + half * 50) * HH + h;
            const float* e = s_tn + half * 50;
            float a0 = 0.f, a1 = 0.f;
#pragma unroll 5
            for (int q = 0; q < 50; q += 2) {
                a0 = fmaf(e[q + 0], wp[(q + 0) * HH], a0);
                a1 = fmaf(e[q + 1], wp[(q + 1) * HH], a1);
            }
            spart[t] = a0 + a1;
        }
        __syncthreads();
        if (t < 128) u1[b * HH + t] = spart[t] + spart[128 + t];
        // Dfull: parallel product + tree reduce
        __syncthreads();
        if (t < 128)
            spart[t] = s_h[t] * We1[HH + t] +
                       (be0[t] * g_e0[t] * rinv + b_e0[t]) * We1[t];
        __syncthreads();
        if (t < 64) {
            float v = spart[t] + spart[t + 64];
            v += __shfl_xor(v, 1);  v += __shfl_xor(v, 2);
            v += __shfl_xor(v, 4);  v += __shfl_xor(v, 8);
            v += __shfl_xor(v, 16); v += __shfl_xor(v, 32);
            if (t == 0) Dfull[b] = v + be1[0];
        }
        return;
    }
    // ---- vi/vj ----
    if (t < 128) sX[t] = g_e0[t] * We1[t] * rinv;
    __syncthreads();
    if (t < 128) {
        float a = 0.f, cc = 0.f;
        for (int hh = 0; hh < HH; ++hh) {
            a = fmaf(We0[t * HH + hh], sX[hh], a);
            cc = fmaf(We0[(HH + t) * HH + hh], sX[hh], cc);
        }
        vi[t] = a;
        vj[t] = cc;
    }
}

// ====== layer 1 (r12-verified): y = relu(bn(dinv_i*(sum_j at_ij sZ_j) + rs*u1 + bg1)) ==
__global__ __launch_bounds__(256, 2) void k_l1(
    const float* __restrict__ X, const float* __restrict__ dinv,
    const float* __restrict__ Wg1, const float* __restrict__ u1,
    const float* __restrict__ rs, const float* __restrict__ bg1,
    const float* __restrict__ g1, const float* __restrict__ bb1,
    float* __restrict__ out) {
    __shared__ float sZ[NN * 20];
    __shared__ float sdv[NN];
    const int b = blockIdx.x, hc = blockIdx.y * HC;
    const int t = threadIdx.x, jp = t & 3, ig = t >> 2;
    if (t < NN) sdv[t] = dinv[b * NN + t];
    __syncthreads();
    for (int idx = t; idx < 400; idx += 256) {
        int j = idx >> 2, c4 = idx & 3;
        float4 w = *(const float4*)&Wg1[j * HH + hc + c4 * 4];
        float dj = sdv[j];
        *(float4*)&sZ[j * 20 + c4 * 4] = make_float4(dj * w.x, dj * w.y, dj * w.z, dj * w.w);
    }
    __syncthreads();
    const int r0 = ig, r1 = (ig < 36) ? 64 + ig : ig;
    float a0[16], a1[16];
#pragma unroll
    for (int c = 0; c < 16; ++c) { a0[c] = 0.f; a1[c] = 0.f; }
    const float* __restrict__ Xb = X + b * NN * NN;
    const int j0 = jp * 28;
#pragma unroll
    for (int s = 0; s < 7; ++s) {
        const int j = j0 + s * 4;
        if (j < NN) {
            float4 v0 = *(const float4*)&Xb[r0 * NN + j];
            float4 v1 = *(const float4*)&Xb[r1 * NN + j];
#pragma unroll
            for (int jj = 0; jj < 4; ++jj) {
                const float e0 = (&v0.x)[jj], e1 = (&v1.x)[jj];
                const int zr = (j + jj) * 20;
#pragma unroll
                for (int c4 = 0; c4 < 4; ++c4) {
                    float4 z = *(const float4*)&sZ[zr + c4 * 4];
                    a0[c4 * 4 + 0] = fmaf(e0, z.x, a0[c4 * 4 + 0]);
                    a0[c4 * 4 + 1] = fmaf(e0, z.y, a0[c4 * 4 + 1]);
                    a0[c4 * 4 + 2] = fmaf(e0, z.z, a0[c4 * 4 + 2]);
                    a0[c4 * 4 + 3] = fmaf(e0, z.w, a0[c4 * 4 + 3]);
                    a1[c4 * 4 + 0] = fmaf(e1, z.x, a1[c4 * 4 + 0]);
                    a1[c4 * 4 + 1] = fmaf(e1, z.y, a1[c4 * 4 + 1]);
                    a1[c4 * 4 + 2] = fmaf(e1, z.z, a1[c4 * 4 + 2]);
                    a1[c4 * 4 + 3] = fmaf(e1, z.w, a1[c4 * 4 + 3]);
                }
            }
        }
    }
#pragma unroll
    for (int c = 0; c < 16; ++c) {
        a0[c] += __shfl_xor(a0[c], 1); a0[c] += __shfl_xor(a0[c], 2);
        a1[c] += __shfl_xor(a1[c], 1); a1[c] += __shfl_xor(a1[c], 2);
    }
    if (jp == 0) {
        const float rinv = 1.0f / sqrtf(1.f + EPSBN);
        const float di0 = sdv[r0], di1 = sdv[r1];
        const float cr0 = 1.f - Xb[r0 * NN + r0];
        const float cr1 = 1.f - Xb[r1 * NN + r1];
        const float rs0 = rs[b * NN + r0], rs1 = rs[b * NN + r1];
        float* ob = out + b * NN * HH;
#pragma unroll
        for (int c4 = 0; c4 < 4; ++c4) {
            float4 gv = *(const float4*)&g1[hc + c4 * 4];
            float4 bbv = *(const float4*)&bb1[hc + c4 * 4];
            float4 bgv = *(const float4*)&bg1[hc + c4 * 4];
            float4 uv = *(const float4*)&u1[b * HH + hc + c4 * 4];
            float4 y0, y1;
#pragma unroll
            for (int cc = 0; cc < 4; ++cc) {
                const int c = c4 * 4 + cc;
                float s0 = di0 * fmaf(cr0, sZ[r0 * 20 + c], a0[c]);
                float s1 = di1 * fmaf(cr1, sZ[r1 * 20 + c], a1[c]);
                (&y0.x)[cc] = fmaxf(fmaf((&gv.x)[cc] * rinv,
                                         s0 + rs0 * (&uv.x)[cc] + (&bgv.x)[cc],
                                         (&bbv.x)[cc]), 0.f);
                (&y1.x)[cc] = fmaxf(fmaf((&gv.x)[cc] * rinv,
                                         s1 + rs1 * (&uv.x)[cc] + (&bgv.x)[cc],
                                         (&bbv.x)[cc]), 0.f);
            }
            *(float4*)&ob[r0 * HH + hc + c4 * 4] = y0;
            if (ig < 36) *(float4*)&ob[r1 * HH + hc + c4 * 4] = y1;
        }
    }
}

// ====== fused layer (r12-verified): z = x@Wtile (k-split); y = dinv-scaled X@z ======
template <bool LAST>
__global__ __launch_bounds__(256, 2) void k_layer(
    const float* __restrict__ X, const float* __restrict__ dinv,
    const float* __restrict__ xin, const float* __restrict__ W,
    const float* __restrict__ bg, const float* __restrict__ g,
    const float* __restrict__ bb, const float* __restrict__ vi,
    const float* __restrict__ vj, float* __restrict__ out,
    float* __restrict__ psi, float* __restrict__ psj) {
    __shared__ float sW[128 * 16];  // [k'][16], k' = (k&31)*4 + (k>>5)
    __shared__ float sZ[NN * 20];
    __shared__ float sdv[NN];
    const int b = blockIdx.x, hcb = blockIdx.y, hc = hcb * HC;
    const int t = threadIdx.x, jp = t & 3, ig = t >> 2;
    if (t < NN) sdv[t] = dinv[b * NN + t];
    for (int idx = t; idx < 512; idx += 256) {
        int k = idx >> 2, c4 = idx & 3;
        int kp = ((k & 31) << 2) | (k >> 5);
        *(float4*)&sW[kp * 16 + c4 * 4] = *(const float4*)&W[k * HH + hc + c4 * 4];
    }
    __syncthreads();
    const int r0 = ig, r1 = (ig < 36) ? 64 + ig : ig;
    const float* __restrict__ xb = xin + b * NN * HH;
    float a0[16], a1[16];
#pragma unroll
    for (int c = 0; c < 16; ++c) { a0[c] = 0.f; a1[c] = 0.f; }
    const int wb = jp << 4;
#pragma unroll
    for (int s = 0; s < 8; ++s) {
        const int k = (jp << 5) + s * 4;
        float4 x0 = *(const float4*)&xb[r0 * HH + k];
        float4 x1 = *(const float4*)&xb[r1 * HH + k];
#pragma unroll
        for (int kk = 0; kk < 4; ++kk) {
            const float e0 = (&x0.x)[kk], e1 = (&x1.x)[kk];
            const int wr = ((s * 4 + kk) << 6) + wb;
#pragma unroll
            for (int c4 = 0; c4 < 4; ++c4) {
                float4 w = *(const float4*)&sW[wr + c4 * 4];
                a0[c4 * 4 + 0] = fmaf(e0, w.x, a0[c4 * 4 + 0]);
                a0[c4 * 4 + 1] = fmaf(e0, w.y, a0[c4 * 4 + 1]);
                a0[c4 * 4 + 2] = fmaf(e0, w.z, a0[c4 * 4 + 2]);
                a0[c4 * 4 + 3] = fmaf(e0, w.w, a0[c4 * 4 + 3]);
                a1[c4 * 4 + 0] = fmaf(e1, w.x, a1[c4 * 4 + 0]);
                a1[c4 * 4 + 1] = fmaf(e1, w.y, a1[c4 * 4 + 1]);
                a1[c4 * 4 + 2] = fmaf(e1, w.z, a1[c4 * 4 + 2]);
                a1[c4 * 4 + 3] = fmaf(e1, w.w, a1[c4 * 4 + 3]);
            }
        }
    }
#pragma unroll
    for (int c = 0; c < 16; ++c) {
        a0[c] += __shfl_xor(a0[c], 1); a0[c] += __shfl_xor(a0[c], 2);
        a1[c] += __shfl_xor(a1[c], 1); a1[c] += __shfl_xor(a1[c], 2);
    }
    if (jp == 0) {
        const float di0 = sdv[r0], di1 = sdv[r1];
#pragma unroll
        for (int c4 = 0; c4 < 4; ++c4) {
            *(float4*)&sZ[r0 * 20 + c4 * 4] =
                make_float4(di0 * a0[c4 * 4 + 0], di0 * a0[c4 * 4 + 1],
                            di0 * a0[c4 * 4 + 2], di0 * a0[c4 * 4 + 3]);
            if (ig < 36)
                *(float4*)&sZ[r1 * 20 + c4 * 4] =
                    make_float4(di1 * a1[c4 * 4 + 0], di1 * a1[c4 * 4 + 1],
                                di1 * a1[c4 * 4 + 2], di1 * a1[c4 * 4 + 3]);
        }
    }
    __syncthreads();
#pragma unroll
    for (int c = 0; c < 16; ++c) { a0[c] = 0.f; a1[c] = 0.f; }
    const float* __restrict__ Xb = X + b * NN * NN;
    const int j0 = jp * 28;
#pragma unroll
    for (int s = 0; s < 7; ++s) {
        const int j = j0 + s * 4;
        if (j < NN) {
            float4 v0 = *(const float4*)&Xb[r0 * NN + j];
            float4 v1 = *(const float4*)&Xb[r1 * NN + j];
#pragma unroll
            for (int jj = 0; jj < 4; ++jj) {
                const float e0 = (&v0.x)[jj], e1 = (&v1.x)[jj];
                const int zr = (j + jj) * 20;
#pragma unroll
                for (int c4 = 0; c4 < 4; ++c4) {
                    float4 z = *(const float4*)&sZ[zr + c4 * 4];
                    a0[c4 * 4 + 0] = fmaf(e0, z.x, a0[c4 * 4 + 0]);
                    a0[c4 * 4 + 1] = fmaf(e0, z.y, a0[c4 * 4 + 1]);
                    a0[c4 * 4 + 2] = fmaf(e0, z.z, a0[c4 * 4 + 2]);
                    a0[c4 * 4 + 3] = fmaf(e0, z.w, a0[c4 * 4 + 3]);
                    a1[c4 * 4 + 0] = fmaf(e1, z.x, a1[c4 * 4 + 0]);
                    a1[c4 * 4 + 1] = fmaf(e1, z.y, a1[c4 * 4 + 1]);
                    a1[c4 * 4 + 2] = fmaf(e1, z.z, a1[c4 * 4 + 2]);
                    a1[c4 * 4 + 3] = fmaf(e1, z.w, a1[c4 * 4 + 3]);
                }
            }
        }
    }
#pragma unroll
    for (int c = 0; c < 16; ++c) {
        a0[c] += __shfl_xor(a0[c], 1); a0[c] += __shfl_xor(a0[c], 2);
        a1[c] += __shfl_xor(a1[c], 1); a1[c] += __shfl_xor(a1[c], 2);
    }
    if (jp == 0) {
        const float rinv = 1.0f / sqrtf(1.f + EPSBN);
        const float di0 = sdv[r0], di1 = sdv[r1];
        const float cr0 = 1.f - Xb[r0 * NN + r0];
        const float cr1 = 1.f - Xb[r1 * NN + r1];
        float y0[16], y1[16];
#pragma unroll
        for (int c4 = 0; c4 < 4; ++c4) {
            float4 gv = *(const float4*)&g[hc + c4 * 4];
            float4 bbv = *(const float4*)&bb[hc + c4 * 4];
            float4 bgv = *(const float4*)&bg[hc + c4 * 4];
#pragma unroll
            for (int cc = 0; cc < 4; ++cc) {
                const int c = c4 * 4 + cc;
                float s0 = di0 * fmaf(cr0, sZ[r0 * 20 + c], a0[c]);
                float s1 = di1 * fmaf(cr1, sZ[r1 * 20 + c], a1[c]);
                y0[c] = fmaxf(fmaf((&gv.x)[cc] * rinv, s0 + (&bgv.x)[cc], (&bbv.x)[cc]), 0.f);
                y1[c] = fmaxf(fmaf((&gv.x)[cc] * rinv, s1 + (&bgv.x)[cc], (&bbv.x)[cc]), 0.f);
            }
        }
        if (LAST) {
            float pi0 = 0.f, pj0 = 0.f, pi1 = 0.f, pj1 = 0.f;
#pragma unroll
            for (int c = 0; c < 16; ++c) {
                const float vic = vi[hc + c], vjc = vj[hc + c];
                pi0 = fmaf(y0[c], vic, pi0); pj0 = fmaf(y0[c], vjc, pj0);
                pi1 = fmaf(y1[c], vic, pi1); pj1 = fmaf(y1[c], vjc, pj1);
            }
            psi[(b * NN + r0) * NCH + hcb] = pi0;
            psj[(b * NN + r0) * NCH + hcb] = pj0;
            if (ig < 36) {
                psi[(b * NN + r1) * NCH + hcb] = pi1;
                psj[(b * NN + r1) * NCH + hcb] = pj1;
            }
        } else {
            float* ob = out + b * NN * HH;
#pragma unroll
            for (int c4 = 0; c4 < 4; ++c4) {
                *(float4*)&ob[r0 * HH + hc + c4 * 4] =
                    make_float4(y0[c4 * 4 + 0], y0[c4 * 4 + 1], y0[c4 * 4 + 2], y0[c4 * 4 + 3]);
                if (ig < 36)
                    *(float4*)&ob[r1 * HH + hc + c4 * 4] =
                        make_float4(y1[c4 * 4 + 0], y1[c4 * 4 + 1], y1[c4 * 4 + 2], y1[c4 * 4 + 3]);
            }
        }
    }
}

// ============ out[b,i,j] = (i!=j) * bn(si+sj+D) (r12-verified) ============
__global__ __launch_bounds__(256) void k_out(
    const float* __restrict__ psi, const float* __restrict__ psj,
    const float* __restrict__ Dfull, const float* __restrict__ g_e1,
    const float* __restrict__ b_e1, float* __restrict__ outp) {
    __shared__ float ssi[25], ssj[NN];
    const int b = blockIdx.x, i0 = blockIdx.y * 25;
    const int t = threadIdx.x;
    if (t < NN) {
        float s = 0.f;
        const float4* p = (const float4*)(psj + (b * NN + t) * NCH);
#pragma unroll
        for (int q = 0; q < NCH / 4; ++q) {
            float4 v = p[q];
            s += v.x + v.y + v.z + v.w;
        }
        ssj[t] = s;
    }
    if (t >= 128 && t < 128 + 25) {
        int i = t - 128;
        float s = 0.f;
        const float4* p = (const float4*)(psi + (b * NN + i0 + i) * NCH);
#pragma unroll
        for (int q = 0; q < NCH / 4; ++q) {
            float4 v = p[q];
            s += v.x + v.y + v.z + v.w;
        }
        ssi[i] = s;
    }
    __syncthreads();
    const float rinv = 1.0f / sqrtf(1.f + EPSBN);
    const float D = Dfull[b], ge = g_e1[0] * rinv, be = b_e1[0];
    float* ob = outp + b * NN * NN + i0 * NN;
    for (int e = t; e < 25 * NN; e += 256) {
        int ii = e / NN, j = e - ii * NN;
        float v = fmaf(ge, ssi[ii] + ssj[j] + D, be);
        ob[e] = (i0 + ii == j) ? 0.f : v;
    }
}

extern "C" void kernel_launch(void* const* d_in, const int* in_sizes, int n_in,
                              void* d_out, int out_size, void* d_ws, size_t ws_size,
                              hipStream_t stream) {
    const float* X    = (const float*)d_in[0];
    const float* timev= (const float*)d_in[1];
    const float* Wt1  = (const float*)d_in[2];
    const float* bt1  = (const float*)d_in[3];
    const float* Wt2  = (const float*)d_in[4];
    const float* bt2  = (const float*)d_in[5];
    const float* Wtn  = (const float*)d_in[6];
    const float* btn  = (const float*)d_in[7];
    const float* g_tn = (const float*)d_in[8];
    const float* b_tn = (const float*)d_in[9];
    const float* Wg1  = (const float*)d_in[10];
    const float* bg1  = (const float*)d_in[11];
    const float* g1   = (const float*)d_in[12];
    const float* bb1  = (const float*)d_in[13];
    const float* Wg2  = (const float*)d_in[14];
    const float* bg2  = (const float*)d_in[15];
    const float* g2   = (const float*)d_in[16];
    const float* bb2  = (const float*)d_in[17];
    const float* Wg3  = (const float*)d_in[18];
    const float* bg3  = (const float*)d_in[19];
    const float* g3   = (const float*)d_in[20];
    const float* bb3  = (const float*)d_in[21];
    const float* We0  = (const float*)d_in[22];
    const float* be0  = (const float*)d_in[23];
    const float* g_e0 = (const float*)d_in[24];
    const float* b_e0 = (const float*)d_in[25];
    const float* We1  = (const float*)d_in[26];
    const float* be1  = (const float*)d_in[27];
    const float* g_e1 = (const float*)d_in[28];
    const float* b_e1 = (const float*)d_in[29];

    float* ws = (float*)d_ws;
    float* dinv  = ws;            // 6400
    float* rs    = dinv + 6400;   // 6400
    float* u1    = rs + 6400;     // 8192
    float* Dfull = u1 + 8192;     // 64
    float* vi    = Dfull + 64;    // 128
    float* vj    = vi + 128;      // 128
    float* x1    = vj + 128;      // 819200 (dead after layer2 -> psi/psj alias)
    float* x2    = x1 + 819200;   // 819200
    float* psi   = x1;            // 51200
    float* psj   = x1 + 51200;    // 51200

    k_pre<<<dim3(2 * NB + 1), dim3(256), 0, stream>>>(
        X, timev, Wt1, bt1, Wt2, bt2, Wtn, btn, g_tn, b_tn, Wg1, We0, We1, be1,
        be0, g_e0, b_e0, dinv, rs, u1, Dfull, vi, vj);

    k_l1<<<dim3(NB, NCH), dim3(256), 0, stream>>>(X, dinv, Wg1, u1, rs, bg1, g1, bb1, x1);
    k_layer<false><<<dim3(NB, NCH), dim3(256), 0, stream>>>(X, dinv, x1, Wg2, bg2, g2,
                                                            bb2, nullptr, nullptr, x2,
                                                            nullptr, nullptr);
    k_layer<true><<<dim3(NB, NCH), dim3(256), 0, stream>>>(X, dinv, x2, Wg3, bg3, g3,
                                                           bb3, vi, vj, nullptr, psi, psj);

    k_out<<<dim3(NB, 4), dim3(256), 0, stream>>>(psi, psj, Dfull, g_e1, b_e1,
                                                 (float*)d_out);
}